// Round 13
// baseline (2150.329 us; speedup 1.0000x reference)
//
#include <hip/hip_runtime.h>
#include <hip/hip_bf16.h>

using short8  = __attribute__((ext_vector_type(8))) short;
using float4v = __attribute__((ext_vector_type(4))) float;
using uint2v  = __attribute__((ext_vector_type(2))) unsigned int;
using u32 = unsigned int;
using u16 = unsigned short;

#define MFMA(a,b,cc) __builtin_amdgcn_mfma_f32_16x16x32_bf16((a),(b),(cc),0,0,0)
// barrier draining only LDS ops: global prefetch stays in flight across it
#define PIPE_BARRIER() asm volatile("s_waitcnt lgkmcnt(0)\n\ts_barrier" ::: "memory")
#define LOG2E 1.44269504088896340736f

static __device__ __forceinline__ float fexp2(float x){ return __builtin_amdgcn_exp2f(x); }
static __device__ __forceinline__ float frcp(float x){ return __builtin_amdgcn_rcpf(x); }

static __device__ __forceinline__ short f2bf(float f){
  __hip_bfloat16 h = __float2bfloat16(f);
  return __builtin_bit_cast(short, h);
}
// weight load with per-gate log2e folding
static __device__ __forceinline__ short8 load_bf8s(const float* p, float s){
  short8 v;
#pragma unroll
  for (int j = 0; j < 8; ++j) v[j] = f2bf(p[j] * s);
  return v;
}
static __device__ __forceinline__ float bflo(u32 d){ return __builtin_bit_cast(float, d << 16); }
static __device__ __forceinline__ float bfhi(u32 d){ return __builtin_bit_cast(float, d & 0xffff0000u); }

// gate math with pre-scaled preactivations (i,f,o: -log2e; g: +2log2e)
static __device__ __forceinline__ float gates1(float ai, float af, float ag, float ao, float& cst){
  float iv = frcp(1.f + fexp2(ai));
  float fv = frcp(1.f + fexp2(af));
  float ov = frcp(1.f + fexp2(ao));
  float gv = 1.f - 2.f * frcp(1.f + fexp2(ag));
  float cn = fv * cst + iv * gv;
  cst = cn;
  float tc = 1.f - 2.f * frcp(1.f + fexp2((2.f*LOG2E) * cn));
  return ov * tc;
}

// ---------------- 8-timestep GEMM producer (batch 2: M=16 = 8t x 2b) -------
// A-frag row = c: dt = c>>1 (0..7), b = c&1. Window KK of each 8-window group
// runs k-frag KK: 8 cvts + 4 MFMA + refill xr[KK] for group t0+8.
template<int KK>
static __device__ __forceinline__ void gm8_part(int t0, const float* xlane,
    float4v (&xr)[4][2], float4v (&acc)[4], const short8 (&wA)[4][4])
{
  short8 xb;
#pragma unroll
  for (int j = 0; j < 4; ++j){ xb[j] = f2bf(xr[KK][0][j]); xb[4+j] = f2bf(xr[KK][1][j]); }
  int tn = t0 + 8; if (tn > 504) tn = 504;
  const float* nx = xlane + (size_t)tn * 128 + KK*32;
  xr[KK][0] = *(const float4v*)nx;
  xr[KK][1] = *(const float4v*)(nx + 4);
  acc[0] = MFMA(xb, wA[0][KK], acc[0]);
  acc[1] = MFMA(xb, wA[1][KK], acc[1]);
  acc[2] = MFMA(xb, wA[2][KK], acc[2]);
  acc[3] = MFMA(xb, wA[3][KK], acc[3]);
}

// store group t0 (8 timesteps) into 16-slot ring.
// lane (c,kg), reg r: global row = kg*4+r -> dt = kg*2 + (r>>1), b = r&1.
static __device__ __forceinline__ void gm8_store(int t0,
    float4v (&acc)[4], u32 (&xgb)[16][2][132], int c, int kg, int wl)
{
#pragma unroll
  for (int r = 0; r < 4; ++r){
    u32 d0 = (u32)(u16)f2bf(acc[0][r]) | ((u32)(u16)f2bf(acc[1][r]) << 16);
    u32 d1 = (u32)(u16)f2bf(acc[2][r]) | ((u32)(u16)f2bf(acc[3][r]) << 16);
    uint2v dv = {d0, d1};
    const int slot = (t0 + kg*2 + (r >> 1)) & 15;
    *(uint2v*)&xgb[slot][r & 1][(wl*16 + c)*2] = dv;
  }
#pragma unroll
  for (int gt = 0; gt < 4; ++gt) acc[gt] = (float4v){0.f,0.f,0.f,0.f};
}

// ---------------- layer-0 wave step (r10 body, batch-2 guards) -------------
template<int P>
static __device__ __forceinline__ void l0_step(int slot,
    const u32 (&xgb)[16][2][132],
    const short8 (&wA)[4][4], const float (&bs)[4],
    float& cst, __hip_bfloat16 (&h0s)[2][16][72],
    float (*tp)[20], int lane, int c, int kg, int wl)
{
  short8 hf0 = *(const short8*)&h0s[P^1][c][kg*8];
  short8 hf1 = *(const short8*)&h0s[P^1][c][32 + kg*8];
  uint2v xgd = *(const uint2v*)&xgb[slot][kg & 1][(wl*16 + c)*2];
  float4v av[4];
#pragma unroll
  for (int gt = 0; gt < 4; ++gt) av[gt] = (float4v){0.f,0.f,0.f,0.f};
  av[0] = MFMA(hf0, wA[0][0], av[0]); av[1] = MFMA(hf0, wA[1][0], av[1]);
  av[2] = MFMA(hf0, wA[2][0], av[2]); av[3] = MFMA(hf0, wA[3][0], av[3]);
  av[0] = MFMA(hf1, wA[0][1], av[0]); av[1] = MFMA(hf1, wA[1][1], av[1]);
  av[2] = MFMA(hf1, wA[2][1], av[2]); av[3] = MFMA(hf1, wA[3][1], av[3]);
  if (lane < 16){
#pragma unroll
    for (int r = 0; r < 4; ++r){
      float4v t_ = {av[0][r], av[1][r], av[2][r], av[3][r]};
      *(float4v*)&tp[lane][r*4] = t_;
    }
  }
  float4v g4 = *(const float4v*)&tp[c][kg*4];
  float ai = g4[0] + bs[0] + bflo(xgd[0]);
  float af = g4[1] + bs[1] + bfhi(xgd[0]);
  float ag = g4[2] + bs[2] + bflo(xgd[1]);
  float ao = g4[3] + bs[3] + bfhi(xgd[1]);
  float hv = gates1(ai, af, ag, ao, cst);
  if (kg < 2) h0s[P][kg][wl*16 + c] = __float2bfloat16(hv);
}

// ---------------- layer-1 wave step (r10 body, batch-2 guards) -------------
template<int TPAR>
static __device__ __forceinline__ void l1_step(bool last,
    const short8 (&wA)[4][4], const float (&bs)[4],
    float& cst,
    const __hip_bfloat16 (&h0s)[2][16][72], __hip_bfloat16 (&h1s)[2][16][72],
    float (*tp)[20], float (*hfin)[64], int lane, int c, int kg, int wl)
{
  short8 a0 = *(const short8*)&h0s[TPAR][c][kg*8];
  short8 a1 = *(const short8*)&h0s[TPAR][c][32 + kg*8];
  short8 b0 = *(const short8*)&h1s[TPAR^1][c][kg*8];
  short8 b1 = *(const short8*)&h1s[TPAR^1][c][32 + kg*8];
  float4v av[4];
#pragma unroll
  for (int gt = 0; gt < 4; ++gt) av[gt] = (float4v){0.f,0.f,0.f,0.f};
  av[0] = MFMA(a0, wA[0][0], av[0]); av[1] = MFMA(a0, wA[1][0], av[1]);
  av[2] = MFMA(a0, wA[2][0], av[2]); av[3] = MFMA(a0, wA[3][0], av[3]);
  av[0] = MFMA(a1, wA[0][1], av[0]); av[1] = MFMA(a1, wA[1][1], av[1]);
  av[2] = MFMA(a1, wA[2][1], av[2]); av[3] = MFMA(a1, wA[3][1], av[3]);
  av[0] = MFMA(b0, wA[0][2], av[0]); av[1] = MFMA(b0, wA[1][2], av[1]);
  av[2] = MFMA(b0, wA[2][2], av[2]); av[3] = MFMA(b0, wA[3][2], av[3]);
  av[0] = MFMA(b1, wA[0][3], av[0]); av[1] = MFMA(b1, wA[1][3], av[1]);
  av[2] = MFMA(b1, wA[2][3], av[2]); av[3] = MFMA(b1, wA[3][3], av[3]);
  if (lane < 16){
#pragma unroll
    for (int r = 0; r < 4; ++r){
      float4v t_ = {av[0][r], av[1][r], av[2][r], av[3][r]};
      *(float4v*)&tp[lane][r*4] = t_;
    }
  }
  float4v g4 = *(const float4v*)&tp[c][kg*4];
  float hv = gates1(g4[0]+bs[0], g4[1]+bs[1], g4[2]+bs[2], g4[3]+bs[3], cst);
  if (kg < 2){
    h1s[TPAR][kg][wl*16 + c] = __float2bfloat16(hv);
    if (last) hfin[kg][wl*16 + c] = hv;
  }
}

// ============================================================================
// Fused kernel, 2 BLOCKS/CU: 512 blocks x 2 batch rows, 768 threads (12 waves),
// waves_per_eu(6,6) -> 6 waves/SIMD so two blocks co-reside and fill each
// other's barrier/chain stalls. Roles as round 10 (best): L0 waves 0-3 (step w),
// L1 waves 4-7 (step w-1), GEMM waves 8-11 -- now 8-timestep-batched
// (M=16 = 8t x 2b) with a 16-slot xg ring, parts spread one per window.
// ============================================================================
__global__ __attribute__((amdgpu_flat_work_group_size(768, 768), amdgpu_waves_per_eu(6, 6)))
void lstm_fused(
    const float* __restrict__ x,
    const float* __restrict__ Wih0, const float* __restrict__ Whh0,
    const float* __restrict__ bih0, const float* __restrict__ bhh0,
    const float* __restrict__ Wih1, const float* __restrict__ Whh1,
    const float* __restrict__ bih1, const float* __restrict__ bhh1,
    const float* __restrict__ fcw,  const float* __restrict__ fcb,
    float* __restrict__ out)
{
  constexpr int T = 512;
  const int tid  = threadIdx.x;
  const int lane = tid & 63;
  const int wv   = tid >> 6;     // 0..11
  const int grp  = wv >> 2;      // 0: L0, 1: L1, 2: GEMM
  const int wl   = wv & 3;
  const int c    = lane & 15;
  const int kg   = lane >> 4;
  const int bblk = blockIdx.x;   // 2-batch block (0..511)

  __shared__ __align__(16) __hip_bfloat16 h0s[2][16][72];
  __shared__ __align__(16) __hip_bfloat16 h1s[2][16][72];
  __shared__ __align__(16) u32  xgb[16][2][132];  // [slot t&15][batch][unit*2+pair]
  __shared__ __align__(16) float tmp[2][4][16][20];
  __shared__ float hfin[2][64];

  { // zero h buffers (rows 2-15 must stay zero: they feed MFMA A-frags)
    __hip_bfloat16 z = __float2bfloat16(0.f);
    for (int i = tid; i < 2*16*72; i += 768){
      (&h0s[0][0][0])[i] = z;
      (&h1s[0][0][0])[i] = z;
    }
  }

  // per-gate log2e folding: i,f,o -> -log2e ; g -> +2*log2e
  const float gsc[4] = {-LOG2E, -LOG2E, 2.f*LOG2E, -LOG2E};

  // ---- unified weight fragments (single 64-VGPR array for all roles) ----
  short8 wA[4][4];
  float  bs[4] = {0.f, 0.f, 0.f, 0.f};
  const int urow = wl*16 + c;
  if (grp == 0){
#pragma unroll
    for (int gt = 0; gt < 4; ++gt){
      const int row = gt*64 + urow;
#pragma unroll
      for (int kk = 0; kk < 2; ++kk){
        wA[gt][kk]   = load_bf8s(Whh0 + row*64 + kk*32 + kg*8, gsc[gt]);
        wA[gt][kk+2] = wA[gt][kk];   // keep defined
      }
      bs[gt] = (bih0[row] + bhh0[row]) * gsc[gt];
    }
  } else if (grp == 1){
#pragma unroll
    for (int gt = 0; gt < 4; ++gt){
      const int row = gt*64 + urow;
#pragma unroll
      for (int kk = 0; kk < 2; ++kk){
        wA[gt][kk]   = load_bf8s(Wih1 + row*64 + kk*32 + kg*8, gsc[gt]);
        wA[gt][kk+2] = load_bf8s(Whh1 + row*64 + kk*32 + kg*8, gsc[gt]);
      }
      bs[gt] = (bih1[row] + bhh1[row]) * gsc[gt];
    }
  } else {
#pragma unroll
    for (int gt = 0; gt < 4; ++gt){
      const int row = gt*64 + urow;
#pragma unroll
      for (int kk = 0; kk < 4; ++kk)
        wA[gt][kk] = load_bf8s(Wih0 + row*128 + kk*32 + kg*8, gsc[gt]);
    }
  }

  // ---- producer x register block + gate accumulators ----
  // lane (c,kg): batch c&1, timestep-in-group c>>1, k-slice kg*8.
  const float* xlane = nullptr;
  float4v xr[4][2];
  float4v acc[4];
#pragma unroll
  for (int gt = 0; gt < 4; ++gt) acc[gt] = (float4v){0.f,0.f,0.f,0.f};
  if (grp == 2){
    xlane = x + (size_t)(bblk*2 + (c & 1)) * T * 128 + (c >> 1)*128 + kg*8;
#pragma unroll
    for (int kk = 0; kk < 4; ++kk){
      xr[kk][0] = *(const float4v*)(xlane + kk*32);
      xr[kk][1] = *(const float4v*)(xlane + kk*32 + 4);
    }
  }
  float cst = 0.f;
  float (*tp)[20] = tmp[grp & 1][wl];   // rec waves only (grp 0/1)

  __syncthreads();  // zero-init visible

  // ---- prologue: produce group 0 (slots 0-7); refills point at group 8 ----
  if (grp == 2){
    gm8_part<0>(0, xlane, xr, acc, wA);
    gm8_part<1>(0, xlane, xr, acc, wA);
    gm8_part<2>(0, xlane, xr, acc, wA);
    gm8_part<3>(0, xlane, xr, acc, wA);
    gm8_store(0, acc, xgb, c, kg, wl);
  }
  PIPE_BARRIER();

  // ---- main: 512 windows in groups of 8; producer makes group lt+8 ----
  for (int lt = 0; lt < T; lt += 8){
    const int t0 = lt + 8;
    const bool prod = (lt < 504);
    // window lt+0
    if (grp == 0) l0_step<0>((lt+0)&15, xgb, wA, bs, cst, h0s, tp, lane, c, kg, wl);
    else if (grp == 1){ if (lt > 0) l1_step<1>(false, wA, bs, cst, h0s, h1s, tp, hfin, lane, c, kg, wl); }
    else if (prod) gm8_part<0>(t0, xlane, xr, acc, wA);
    PIPE_BARRIER();
    // window lt+1
    if (grp == 0) l0_step<1>((lt+1)&15, xgb, wA, bs, cst, h0s, tp, lane, c, kg, wl);
    else if (grp == 1) l1_step<0>(false, wA, bs, cst, h0s, h1s, tp, hfin, lane, c, kg, wl);
    else if (prod) gm8_part<1>(t0, xlane, xr, acc, wA);
    PIPE_BARRIER();
    // window lt+2
    if (grp == 0) l0_step<0>((lt+2)&15, xgb, wA, bs, cst, h0s, tp, lane, c, kg, wl);
    else if (grp == 1) l1_step<1>(false, wA, bs, cst, h0s, h1s, tp, hfin, lane, c, kg, wl);
    else if (prod) gm8_part<2>(t0, xlane, xr, acc, wA);
    PIPE_BARRIER();
    // window lt+3
    if (grp == 0) l0_step<1>((lt+3)&15, xgb, wA, bs, cst, h0s, tp, lane, c, kg, wl);
    else if (grp == 1) l1_step<0>(false, wA, bs, cst, h0s, h1s, tp, hfin, lane, c, kg, wl);
    else if (prod) gm8_part<3>(t0, xlane, xr, acc, wA);
    PIPE_BARRIER();
    // window lt+4
    if (grp == 0) l0_step<0>((lt+4)&15, xgb, wA, bs, cst, h0s, tp, lane, c, kg, wl);
    else if (grp == 1) l1_step<1>(false, wA, bs, cst, h0s, h1s, tp, hfin, lane, c, kg, wl);
    else if (prod) gm8_store(t0, acc, xgb, c, kg, wl);
    PIPE_BARRIER();
    // window lt+5
    if (grp == 0) l0_step<1>((lt+5)&15, xgb, wA, bs, cst, h0s, tp, lane, c, kg, wl);
    else if (grp == 1) l1_step<0>(false, wA, bs, cst, h0s, h1s, tp, hfin, lane, c, kg, wl);
    PIPE_BARRIER();
    // window lt+6
    if (grp == 0) l0_step<0>((lt+6)&15, xgb, wA, bs, cst, h0s, tp, lane, c, kg, wl);
    else if (grp == 1) l1_step<1>(false, wA, bs, cst, h0s, h1s, tp, hfin, lane, c, kg, wl);
    PIPE_BARRIER();
    // window lt+7
    if (grp == 0) l0_step<1>((lt+7)&15, xgb, wA, bs, cst, h0s, tp, lane, c, kg, wl);
    else if (grp == 1) l1_step<0>(false, wA, bs, cst, h0s, h1s, tp, hfin, lane, c, kg, wl);
    PIPE_BARRIER();
  }
  // epilogue: L1 t1 = 511 (odd parity)
  if (grp == 1)
    l1_step<1>(true, wA, bs, cst, h0s, h1s, tp, hfin, lane, c, kg, wl);
  __syncthreads();

  // FC head: out[b] = sigmoid(h1_last . fcw + fcb)
  if (tid < 2){
    float s = fcb[0];
#pragma unroll
    for (int k = 0; k < 64; ++k) s += hfin[tid][k] * fcw[k];
    out[bblk*2 + tid] = frcp(1.f + fexp2(-LOG2E * s));
  }
}

extern "C" void kernel_launch(void* const* d_in, const int* in_sizes, int n_in,
                              void* d_out, int out_size, void* d_ws, size_t ws_size,
                              hipStream_t stream) {
  const float* x    = (const float*)d_in[0];
  const float* Wih0 = (const float*)d_in[1];
  const float* Whh0 = (const float*)d_in[2];
  const float* bih0 = (const float*)d_in[3];
  const float* bhh0 = (const float*)d_in[4];
  const float* Wih1 = (const float*)d_in[5];
  const float* Whh1 = (const float*)d_in[6];
  const float* bih1 = (const float*)d_in[7];
  const float* bhh1 = (const float*)d_in[8];
  const float* fcw  = (const float*)d_in[9];
  const float* fcb  = (const float*)d_in[10];
  float* out = (float*)d_out;

  hipLaunchKernelGGL(lstm_fused, dim3(512), dim3(768), 0, stream,
                     x, Wih0, Whh0, bih0, bhh0, Wih1, Whh1, bih1, bhh1,
                     fcw, fcb, out);
}

// Round 14
// 332.838 us; speedup vs baseline: 6.4606x; 6.4606x over previous
//
#include <hip/hip_runtime.h>
#include <hip/hip_bf16.h>

using short8  = __attribute__((ext_vector_type(8))) short;
using float4v = __attribute__((ext_vector_type(4))) float;
using uint2v  = __attribute__((ext_vector_type(2))) unsigned int;
using u32 = unsigned int;
using u16 = unsigned short;

#define MFMA(a,b,cc) __builtin_amdgcn_mfma_f32_16x16x32_bf16((a),(b),(cc),0,0,0)
// barrier draining only LDS ops: global prefetch stays in flight across it
#define PIPE_BARRIER() asm volatile("s_waitcnt lgkmcnt(0)\n\ts_barrier" ::: "memory")
#define LOG2E 1.44269504088896340736f

static __device__ __forceinline__ float fexp2(float x){ return __builtin_amdgcn_exp2f(x); }
static __device__ __forceinline__ float frcp(float x){ return __builtin_amdgcn_rcpf(x); }

static __device__ __forceinline__ short f2bf(float f){
  __hip_bfloat16 h = __float2bfloat16(f);
  return __builtin_bit_cast(short, h);
}
// weight load with per-gate log2e folding
static __device__ __forceinline__ short8 load_bf8s(const float* p, float s){
  short8 v;
#pragma unroll
  for (int j = 0; j < 8; ++j) v[j] = f2bf(p[j] * s);
  return v;
}
static __device__ __forceinline__ float bflo(u32 d){ return __builtin_bit_cast(float, d << 16); }
static __device__ __forceinline__ float bfhi(u32 d){ return __builtin_bit_cast(float, d & 0xffff0000u); }

// gate math with pre-scaled preactivations (i,f,o: -log2e; g: +2log2e)
static __device__ __forceinline__ float gates1(float ai, float af, float ag, float ao, float& cst){
  float iv = frcp(1.f + fexp2(ai));
  float fv = frcp(1.f + fexp2(af));
  float ov = frcp(1.f + fexp2(ao));
  float gv = 1.f - 2.f * frcp(1.f + fexp2(ag));
  float cn = fv * cst + iv * gv;
  cst = cn;
  float tc = 1.f - 2.f * frcp(1.f + fexp2((2.f*LOG2E) * cn));
  return ov * tc;
}

// ---------------- pipelined 4-timestep GEMM producer ------------------------
// Full-M: A row = (dt = c>>2, batch = c&3). Window KK of each 4-window group
// does k-frag KK only: 8 cvts + 4 MFMA + refill xr[KK] (consumed 4 windows on).
template<int KK>
static __device__ __forceinline__ void gm4_part(int t0, const float* xlane,
    float4v (&xr)[4][2], float4v (&acc)[4], const short8 (&wA)[4][4])
{
  short8 xb;
#pragma unroll
  for (int j = 0; j < 4; ++j){ xb[j] = f2bf(xr[KK][0][j]); xb[4+j] = f2bf(xr[KK][1][j]); }
  // refill xr[KK] with x(group t0+4), k-frag KK (clamped at tail)
  int tn = t0 + 4; if (tn > 508) tn = 508;
  const float* nx = xlane + (size_t)tn * 128 + KK*32;
  xr[KK][0] = *(const float4v*)nx;
  xr[KK][1] = *(const float4v*)(nx + 4);
  acc[0] = MFMA(xb, wA[0][KK], acc[0]);
  acc[1] = MFMA(xb, wA[1][KK], acc[1]);
  acc[2] = MFMA(xb, wA[2][KK], acc[2]);
  acc[3] = MFMA(xb, wA[3][KK], acc[3]);
}

// pack + store group t0 into slots (t0+kg)&7; lane (c,kg) holds
// xg[t0+kg][batch r][unit wl*16+c][gate gt] in acc[gt][r]. Resets acc.
static __device__ __forceinline__ void gm4_store(int t0,
    float4v (&acc)[4], u32 (&xgb)[8][4][132], int c, int kg, int wl)
{
  u32* base = &xgb[(t0 + kg) & 7][0][(wl*16 + c)*2];
#pragma unroll
  for (int r = 0; r < 4; ++r){
    u32 d0 = (u32)(u16)f2bf(acc[0][r]) | ((u32)(u16)f2bf(acc[1][r]) << 16);
    u32 d1 = (u32)(u16)f2bf(acc[2][r]) | ((u32)(u16)f2bf(acc[3][r]) << 16);
    uint2v dv = {d0, d1};
    *(uint2v*)(base + r*132) = dv;
  }
#pragma unroll
  for (int gt = 0; gt < 4; ++gt) acc[gt] = (float4v){0.f,0.f,0.f,0.f};
}

// ---------------- layer-0 wave step: wA[gt][0..1] = Whh0 -------------------
template<int P>
static __device__ __forceinline__ void l0_step(int slot,
    const u32 (&xgb)[8][4][132],
    const short8 (&wA)[4][4], const float (&bs)[4],
    float& cst, __hip_bfloat16 (&h0s)[2][16][72],
    float (*tp)[20], int lane, int c, int kg, int wl)
{
  short8 hf0 = *(const short8*)&h0s[P^1][c][kg*8];
  short8 hf1 = *(const short8*)&h0s[P^1][c][32 + kg*8];
  uint2v xgd = *(const uint2v*)&xgb[slot][kg][(wl*16 + c)*2];
  float4v av[4];
#pragma unroll
  for (int gt = 0; gt < 4; ++gt) av[gt] = (float4v){0.f,0.f,0.f,0.f};
  av[0] = MFMA(hf0, wA[0][0], av[0]); av[1] = MFMA(hf0, wA[1][0], av[1]);
  av[2] = MFMA(hf0, wA[2][0], av[2]); av[3] = MFMA(hf0, wA[3][0], av[3]);
  av[0] = MFMA(hf1, wA[0][1], av[0]); av[1] = MFMA(hf1, wA[1][1], av[1]);
  av[2] = MFMA(hf1, wA[2][1], av[2]); av[3] = MFMA(hf1, wA[3][1], av[3]);
  if (lane < 16){
#pragma unroll
    for (int r = 0; r < 4; ++r){
      float4v t_ = {av[0][r], av[1][r], av[2][r], av[3][r]};
      *(float4v*)&tp[lane][r*4] = t_;
    }
  }
  float4v g4 = *(const float4v*)&tp[c][kg*4];
  float ai = g4[0] + bs[0] + bflo(xgd[0]);
  float af = g4[1] + bs[1] + bfhi(xgd[0]);
  float ag = g4[2] + bs[2] + bflo(xgd[1]);
  float ao = g4[3] + bs[3] + bfhi(xgd[1]);
  float hv = gates1(ai, af, ag, ao, cst);
  h0s[P][kg][wl*16 + c] = __float2bfloat16(hv);
}

// -------- layer-1 wave step: wA[gt][0..1] = Wih1, wA[gt][2..3] = Whh1 ------
template<int TPAR>
static __device__ __forceinline__ void l1_step(bool last,
    const short8 (&wA)[4][4], const float (&bs)[4],
    float& cst,
    const __hip_bfloat16 (&h0s)[2][16][72], __hip_bfloat16 (&h1s)[2][16][72],
    float (*tp)[20], float (*hfin)[64], int lane, int c, int kg, int wl)
{
  short8 a0 = *(const short8*)&h0s[TPAR][c][kg*8];
  short8 a1 = *(const short8*)&h0s[TPAR][c][32 + kg*8];
  short8 b0 = *(const short8*)&h1s[TPAR^1][c][kg*8];
  short8 b1 = *(const short8*)&h1s[TPAR^1][c][32 + kg*8];
  float4v av[4];
#pragma unroll
  for (int gt = 0; gt < 4; ++gt) av[gt] = (float4v){0.f,0.f,0.f,0.f};
  av[0] = MFMA(a0, wA[0][0], av[0]); av[1] = MFMA(a0, wA[1][0], av[1]);
  av[2] = MFMA(a0, wA[2][0], av[2]); av[3] = MFMA(a0, wA[3][0], av[3]);
  av[0] = MFMA(a1, wA[0][1], av[0]); av[1] = MFMA(a1, wA[1][1], av[1]);
  av[2] = MFMA(a1, wA[2][1], av[2]); av[3] = MFMA(a1, wA[3][1], av[3]);
  av[0] = MFMA(b0, wA[0][2], av[0]); av[1] = MFMA(b0, wA[1][2], av[1]);
  av[2] = MFMA(b0, wA[2][2], av[2]); av[3] = MFMA(b0, wA[3][2], av[3]);
  av[0] = MFMA(b1, wA[0][3], av[0]); av[1] = MFMA(b1, wA[1][3], av[1]);
  av[2] = MFMA(b1, wA[2][3], av[2]); av[3] = MFMA(b1, wA[3][3], av[3]);
  if (lane < 16){
#pragma unroll
    for (int r = 0; r < 4; ++r){
      float4v t_ = {av[0][r], av[1][r], av[2][r], av[3][r]};
      *(float4v*)&tp[lane][r*4] = t_;
    }
  }
  float4v g4 = *(const float4v*)&tp[c][kg*4];
  float hv = gates1(g4[0]+bs[0], g4[1]+bs[1], g4[2]+bs[2], g4[3]+bs[3], cst);
  h1s[TPAR][kg][wl*16 + c] = __float2bfloat16(hv);
  if (last) hfin[kg][wl*16 + c] = hv;
}

// ============================================================================
// Round-10 structure (champion, 345us) + persistent wave priority:
// 256 blocks x 4 batch rows, 768 threads (12 waves), 1 block/CU.
// Waves 0-3: layer0 (step w). Waves 4-7: layer1 (step w-1). Waves 8-11: GEMM
// producers (full-M 4-timestep-batched, software-pipelined one part/window).
// NEW (r14): s_setprio set ONCE per role -- L1=2 (longest per-window chain,
// 16 MFMAs), L0=1, GM=0 (has 4-8 windows of slack). At window start all three
// waves/SIMD contend for issue; priority retires the window-critical waves
// first and pushes GM's slack-tolerant work into the stall shadows.
// ============================================================================
__global__ __attribute__((amdgpu_flat_work_group_size(768, 768), amdgpu_waves_per_eu(3, 3)))
void lstm_fused(
    const float* __restrict__ x,
    const float* __restrict__ Wih0, const float* __restrict__ Whh0,
    const float* __restrict__ bih0, const float* __restrict__ bhh0,
    const float* __restrict__ Wih1, const float* __restrict__ Whh1,
    const float* __restrict__ bih1, const float* __restrict__ bhh1,
    const float* __restrict__ fcw,  const float* __restrict__ fcb,
    float* __restrict__ out)
{
  constexpr int T = 512;
  const int tid  = threadIdx.x;
  const int lane = tid & 63;
  const int wv   = tid >> 6;     // 0..11
  const int grp  = wv >> 2;      // 0: L0, 1: L1, 2: GEMM
  const int wl   = wv & 3;
  const int c    = lane & 15;
  const int kg   = lane >> 4;
  const int bblk = blockIdx.x;   // 4-batch block (0..255)

  __shared__ __align__(16) __hip_bfloat16 h0s[2][16][72];
  __shared__ __align__(16) __hip_bfloat16 h1s[2][16][72];
  __shared__ __align__(16) u32  xgb[8][4][132];   // [slot t&7][batch][unit*2+pair]
  __shared__ __align__(16) float tmp[2][4][16][20];
  __shared__ float hfin[4][64];

  { // zero h buffers (rows 4-15 must stay zero: they feed MFMA A-frags)
    __hip_bfloat16 z = __float2bfloat16(0.f);
    for (int i = tid; i < 2*16*72; i += 768){
      (&h0s[0][0][0])[i] = z;
      (&h1s[0][0][0])[i] = z;
    }
  }

  // per-gate log2e folding: i,f,o -> -log2e ; g -> +2*log2e
  const float gsc[4] = {-LOG2E, -LOG2E, 2.f*LOG2E, -LOG2E};

  // ---- unified weight fragments (single 64-VGPR array for all roles) ----
  short8 wA[4][4];
  float  bs[4] = {0.f, 0.f, 0.f, 0.f};
  const int urow = wl*16 + c;
  if (grp == 0){
#pragma unroll
    for (int gt = 0; gt < 4; ++gt){
      const int row = gt*64 + urow;
#pragma unroll
      for (int kk = 0; kk < 2; ++kk){
        wA[gt][kk]   = load_bf8s(Whh0 + row*64 + kk*32 + kg*8, gsc[gt]);
        wA[gt][kk+2] = wA[gt][kk];   // keep defined
      }
      bs[gt] = (bih0[row] + bhh0[row]) * gsc[gt];
    }
  } else if (grp == 1){
#pragma unroll
    for (int gt = 0; gt < 4; ++gt){
      const int row = gt*64 + urow;
#pragma unroll
      for (int kk = 0; kk < 2; ++kk){
        wA[gt][kk]   = load_bf8s(Wih1 + row*64 + kk*32 + kg*8, gsc[gt]);
        wA[gt][kk+2] = load_bf8s(Whh1 + row*64 + kk*32 + kg*8, gsc[gt]);
      }
      bs[gt] = (bih1[row] + bhh1[row]) * gsc[gt];
    }
  } else {
#pragma unroll
    for (int gt = 0; gt < 4; ++gt){
      const int row = gt*64 + urow;
#pragma unroll
      for (int kk = 0; kk < 4; ++kk)
        wA[gt][kk] = load_bf8s(Wih0 + row*128 + kk*32 + kg*8, gsc[gt]);
    }
  }

  // ---- persistent role priority (set once; see header comment) ----
  if (grp == 1)      __builtin_amdgcn_s_setprio(2);
  else if (grp == 0) __builtin_amdgcn_s_setprio(1);
  // grp 2 (GEMM producers) stays at default priority 0

  // ---- producer x register block + gate accumulators ----
  // lane (c,kg): batch c&3, timestep-in-group c>>2, k-slice kg*8.
  const float* xlane = nullptr;
  float4v xr[4][2];
  float4v acc[4];
#pragma unroll
  for (int gt = 0; gt < 4; ++gt) acc[gt] = (float4v){0.f,0.f,0.f,0.f};
  if (grp == 2){
    xlane = x + (size_t)(bblk*4 + (c & 3)) * T * 128 + (c >> 2)*128 + kg*8;
#pragma unroll
    for (int kk = 0; kk < 4; ++kk){
      xr[kk][0] = *(const float4v*)(xlane + kk*32);
      xr[kk][1] = *(const float4v*)(xlane + kk*32 + 4);
    }
  }
  float cst = 0.f;
  float (*tp)[20] = tmp[grp & 1][wl];   // rec waves only (grp 0/1)

  __syncthreads();  // zero-init visible

  // ---- prologue: produce group 0 (slots 0-3); refills point at group 1 ----
  if (grp == 2){
    gm4_part<0>(0, xlane, xr, acc, wA);
    gm4_part<1>(0, xlane, xr, acc, wA);
    gm4_part<2>(0, xlane, xr, acc, wA);
    gm4_part<3>(0, xlane, xr, acc, wA);
    gm4_store(0, acc, xgb, c, kg, wl);
  }
  PIPE_BARRIER();

  // ---- main: 512 windows in groups of 4; producer makes group lt+4 ----
  for (int lt = 0; lt < T; lt += 4){
    const int sb = lt & 7;
    const int t0 = lt + 4;
    const bool prod = (lt <= 504);
    // window lt+0
    if (grp == 0) l0_step<0>(sb+0, xgb, wA, bs, cst, h0s, tp, lane, c, kg, wl);
    else if (grp == 1){ if (lt > 0) l1_step<1>(false, wA, bs, cst, h0s, h1s, tp, hfin, lane, c, kg, wl); }
    else if (prod) gm4_part<0>(t0, xlane, xr, acc, wA);
    PIPE_BARRIER();
    // window lt+1
    if (grp == 0) l0_step<1>(sb+1, xgb, wA, bs, cst, h0s, tp, lane, c, kg, wl);
    else if (grp == 1) l1_step<0>(false, wA, bs, cst, h0s, h1s, tp, hfin, lane, c, kg, wl);
    else if (prod) gm4_part<1>(t0, xlane, xr, acc, wA);
    PIPE_BARRIER();
    // window lt+2
    if (grp == 0) l0_step<0>(sb+2, xgb, wA, bs, cst, h0s, tp, lane, c, kg, wl);
    else if (grp == 1) l1_step<1>(false, wA, bs, cst, h0s, h1s, tp, hfin, lane, c, kg, wl);
    else if (prod) gm4_part<2>(t0, xlane, xr, acc, wA);
    PIPE_BARRIER();
    // window lt+3
    if (grp == 0) l0_step<1>(sb+3, xgb, wA, bs, cst, h0s, tp, lane, c, kg, wl);
    else if (grp == 1) l1_step<0>(false, wA, bs, cst, h0s, h1s, tp, hfin, lane, c, kg, wl);
    else if (prod){ gm4_part<3>(t0, xlane, xr, acc, wA); gm4_store(t0, acc, xgb, c, kg, wl); }
    PIPE_BARRIER();
  }
  // epilogue: L1 t1 = 511 (odd parity)
  if (grp == 1)
    l1_step<1>(true, wA, bs, cst, h0s, h1s, tp, hfin, lane, c, kg, wl);
  __syncthreads();

  // FC head: out[b] = sigmoid(h1_last . fcw + fcb)
  if (tid < 4){
    float s = fcb[0];
#pragma unroll
    for (int k = 0; k < 64; ++k) s += hfin[tid][k] * fcw[k];
    out[bblk*4 + tid] = frcp(1.f + fexp2(-LOG2E * s));
  }
}

extern "C" void kernel_launch(void* const* d_in, const int* in_sizes, int n_in,
                              void* d_out, int out_size, void* d_ws, size_t ws_size,
                              hipStream_t stream) {
  const float* x    = (const float*)d_in[0];
  const float* Wih0 = (const float*)d_in[1];
  const float* Whh0 = (const float*)d_in[2];
  const float* bih0 = (const float*)d_in[3];
  const float* bhh0 = (const float*)d_in[4];
  const float* Wih1 = (const float*)d_in[5];
  const float* Whh1 = (const float*)d_in[6];
  const float* bih1 = (const float*)d_in[7];
  const float* bhh1 = (const float*)d_in[8];
  const float* fcw  = (const float*)d_in[9];
  const float* fcb  = (const float*)d_in[10];
  float* out = (float*)d_out;

  hipLaunchKernelGGL(lstm_fused, dim3(256), dim3(768), 0, stream,
                     x, Wih0, Whh0, bih0, bhh0, Wih1, Whh1, bih1, bhh1,
                     fcw, fcb, out);
}